// Round 1
// baseline (5769.057 us; speedup 1.0000x reference)
//
#include <hip/hip_runtime.h>
#include <stdint.h>

#define T_IN  128
#define T_OUT 50
#define NW    8                         // waves per block (512 threads)
#define RPW   32                        // batch rows per wave
#define HROW_BYTES 144                  // 128B h-row + 16B pad (9 x 16B, balanced banks)
#define HBUF_WAVE  (RPW * HROW_BYTES)   // 4608 B

typedef __bf16 bf16x8_t __attribute__((ext_vector_type(8)));
typedef float  f32x16_t __attribute__((ext_vector_type(16)));

#define LOG2E  1.4426950408889634f
#define LOG2E2 2.8853900817779268f

__device__ __forceinline__ float rcp_f(float x) { return __builtin_amdgcn_rcpf(x); }
__device__ __forceinline__ float ex2(float x)   { return __builtin_amdgcn_exp2f(x); }
__device__ __forceinline__ uint32_t pk(__bf16 a, __bf16 b) {
    return (uint32_t)__builtin_bit_cast(uint16_t, a) |
           ((uint32_t)__builtin_bit_cast(uint16_t, b) << 16);
}
#define MFMA32(A, B, C) __builtin_amdgcn_mfma_f32_32x32x16_bf16(A, B, C, 0, 0, 0)
#define ZERO16 (f32x16_t){0.f,0.f,0.f,0.f,0.f,0.f,0.f,0.f,0.f,0.f,0.f,0.f,0.f,0.f,0.f,0.f}

// 32x32x16 MFMA layouts:
//   C/D (HW-verified m74/m101): col = lane&31, row = (reg&3)+8*(reg>>2)+4*(lane>>5)
//   A: A[m = lane&31][k = (lane>>5)*8 + j];  B: B[k = (lane>>5)*8 + j][n = lane&31]
// Tiles: t = hf*4 + g  (g: 0=i,1=f,2=g,3=o; hf = unit col-half).
// exp2 folding: Whh/Wih/bias pre-scaled by log2e (i,f,o) / 2*log2e (g).
//
// OCCUPANCY PLAY (this round): LDS was the limiter (72704B -> 2 blk/CU -> 2
// waves/SIMD; latency-stall regime, VALUBusy 48%/Mfma 14%/all pipes idle half
// the time). Shrunk to 78848B @ NW=8 -> 2 blk x 8 waves = 16 waves/CU = 4/SIMD.
// VGPR must stay <=128 (launch_bounds(512,4)); previous build was exactly 128.

template<bool DEC>
__device__ __forceinline__ void do_step(
    uint8_t* __restrict__ hb,           // wave's h buffer
    const uint8_t* __restrict__ fragp,  // sFrag + lane*16
    const uint8_t* __restrict__ b2p,    // sB2 + lane*8
    int m, int kh, uint32_t xpack,
    f32x16_t& cstA, f32x16_t& cstB,
    float wfa0, float wfa1, float wfb0, float wfb1,
    float (&s0)[16], float (&s1)[16])
{
    // A-frags: row m, k-groups 0..3 (units kk*16 + kh*8 + j)
    const uint8_t* ha = hb + m * HROW_BYTES + kh * 16;
    bf16x8_t a0 = *(const bf16x8_t*)(ha);
    bf16x8_t a1 = *(const bf16x8_t*)(ha + 32);
    bf16x8_t a2 = *(const bf16x8_t*)(ha + 64);
    bf16x8_t a3 = *(const bf16x8_t*)(ha + 96);
    union { bf16x8_t v; uint32_t u[4]; } ux;
    ux.u[0] = kh ? 0u : xpack;          // k=0,1 : x0, x1
    ux.u[1] = kh ? 0u : 0x00003F80u;    // k=2   : 1.0 (bias row)
    ux.u[2] = 0u; ux.u[3] = 0u;
    bf16x8_t ax = ux.v;

    #pragma unroll
    for (int hf = 0; hf < 2; ++hf) {
        f32x16_t acc[4];
        #pragma unroll
        for (int g = 0; g < 4; ++g) {
            const uint8_t* bp = fragp + (hf * 4 + g) * 4096;
            f32x16_t a = MFMA32(a0, *(const bf16x8_t*)(bp), ZERO16);
            a = MFMA32(a1, *(const bf16x8_t*)(bp + 1024), a);
            a = MFMA32(a2, *(const bf16x8_t*)(bp + 2048), a);
            a = MFMA32(a3, *(const bf16x8_t*)(bp + 3072), a);
            // x/bias slab: only k=0..3 nonzero; LDS holds zeros for kg=1 lanes
            uint2 d2 = *(const uint2*)(b2p + (hf * 4 + g) * 512);
            union { bf16x8_t v; uint32_t u[4]; } bu;
            bu.u[0] = d2.x; bu.u[1] = d2.y; bu.u[2] = 0u; bu.u[3] = 0u;
            acc[g] = MFMA32(ax, bu.v, a);
        }
        f32x16_t& cs = hf ? cstB : cstA;
        const float w0 = hf ? wfb0 : wfa0;
        const float w1 = hf ? wfb1 : wfa1;
        #pragma unroll
        for (int jp = 0; jp < 8; ++jp) {
            const int j0 = 2 * jp, j1 = 2 * jp + 1;
            float og[2], ec[2];
            #pragma unroll
            for (int jj = 0; jj < 2; ++jj) {
                const int j = j0 + jj;
                float ea  = ex2(-acc[0][j]);     // pre-scaled -> bare exp2
                float efv = ex2(-acc[1][j]);
                float egv = ex2(-acc[2][j]);     // g pre-scaled by 2*log2e
                float eov = ex2(-acc[3][j]);
                float pa = 1.f + ea, pfv = 1.f + efv, pg = 1.f + egv, po = 1.f + eov;
                float A  = pa * pg, Bq = pfv * po;
                float rr = rcp_f(A * Bq);
                float rA = rr * A;               // = 1/(pf*po)
                float rB = rr * Bq;              // = 1/(pa*pg)
                float igp = (1.f - egv) * rB;    // = i*g
                float fgt = rA * po;             // = sigmoid(f)
                float ogt = rA * pfv;            // = sigmoid(o)
                float cn  = fgt * cs[j] + igp;
                cs[j] = cn;
                float y = fminf(fmaxf(cn * LOG2E2, -43.f), 43.f);
                ec[jj] = ex2(-y);
                og[jj] = ogt;
            }
            float C0 = 1.f + ec[0], C1 = 1.f + ec[1];
            float rr2 = rcp_f(C0 * C1);
            float h0 = og[0] * (1.f - ec[0]) * rr2 * C1;
            float h1 = og[1] * (1.f - ec[1]) * rr2 * C0;
            if constexpr (DEC) {
                s0[j0] += h0 * w0; s1[j0] += h0 * w1;
                s0[j1] += h1 * w0; s1[j1] += h1 * w1;
            }
            const int r0 = (j0 & 3) + 8 * (j0 >> 2) + 4 * kh;
            const int r1 = (j1 & 3) + 8 * (j1 >> 2) + 4 * kh;
            *((__bf16*)(hb + r0 * HROW_BYTES + hf * 64) + m) = (__bf16)h0;
            *((__bf16*)(hb + r1 * HROW_BYTES + hf * 64) + m) = (__bf16)h1;
        }
    }
}

__global__ __launch_bounds__(512, 4) void seq2seq_lstm(
    const float* __restrict__ in_seq,
    const float* __restrict__ WihE, const float* __restrict__ WhhE,
    const float* __restrict__ bihE, const float* __restrict__ bhhE,
    const float* __restrict__ WihD, const float* __restrict__ WhhD,
    const float* __restrict__ bihD, const float* __restrict__ bhhD,
    const float* __restrict__ Wfc,  const float* __restrict__ bfc,
    float* __restrict__ out)
{
    __shared__ __align__(16) uint8_t sFrag[32768];          // 8 tiles x 4 kfrags x 1KB
    __shared__ __align__(16) uint8_t sB2[4096];             // 8 tiles x 64 lanes x 8B
    __shared__ __align__(16) uint8_t sHbuf[NW * HBUF_WAVE]; // 36864
    __shared__ __align__(16) uint8_t sXbuf[NW * 512];       // [step0..3][row0..31] u32-pack
    __shared__ __align__(16) uint8_t sXfb[NW * 128];        // decoder x feedback (u32-pack)
    // total 78848 B -> 2 blocks/CU (16 waves/CU = 4/SIMD) at VGPR cap 128

    const int tid  = threadIdx.x;
    const int lane = tid & 63;
    const int wave = tid >> 6;
    const int m    = lane & 31;
    const int kh   = lane >> 5;

    auto stage_frags = [&](const float* Whh, const float* Wih,
                           const float* bih, const float* bhh) {
        #pragma unroll 1
        for (int it = 0; it < 4; ++it) {
            int idx = it * 512 + tid;    // 0..2047 = frag(0..31) x lane(0..63)
            int ln  = idx & 63;
            int fg  = idx >> 6;          // fg = t*4 + kk
            int kk  = fg & 3;
            int t   = fg >> 2;
            int g   = t & 3;
            int hf  = t >> 2;
            int n   = ln & 31;
            int kg  = ln >> 5;
            float sc = (g == 2) ? LOG2E2 : LOG2E;
            const float* wr = Whh + (g * 64 + hf * 32 + n) * 64 + kk * 16 + kg * 8;
            uint32_t wv[4];
            #pragma unroll
            for (int jj = 0; jj < 4; ++jj)
                wv[jj] = pk((__bf16)(sc * wr[2 * jj]), (__bf16)(sc * wr[2 * jj + 1]));
            uint32_t* d = (uint32_t*)(sFrag + t * 4096 + kk * 1024 + ln * 16);
            d[0] = wv[0]; d[1] = wv[1]; d[2] = wv[2]; d[3] = wv[3];
        }
        // slab2: per (tile, lane): kg=0 lanes hold {Wih pair, bias pair}; kg=1 zeros
        {
            int ln = tid & 63;
            int t  = tid >> 6;           // 0..7
            int g  = t & 3;
            int hf = t >> 2;
            int n  = ln & 31;
            uint32_t u0 = 0u, u1 = 0u;
            if (ln < 32) {
                float sc = (g == 2) ? LOG2E2 : LOG2E;
                int col = g * 64 + hf * 32 + n;
                u0 = pk((__bf16)(sc * Wih[col * 2 + 0]), (__bf16)(sc * Wih[col * 2 + 1]));
                u1 = pk((__bf16)(sc * (bih[col] + bhh[col])), (__bf16)0.0f);
            }
            uint32_t* d = (uint32_t*)(sB2 + t * 512 + ln * 8);
            d[0] = u0; d[1] = u1;
        }
    };

    stage_frags(WhhE, WihE, bihE, bhhE);
    for (int i = tid; i < (NW * HBUF_WAVE) / 4; i += 512)
        ((uint32_t*)sHbuf)[i] = 0u;
    __syncthreads();
    // ---- no barriers inside the time loops: each wave owns its 32 rows ----

    uint8_t* hb    = sHbuf + wave * HBUF_WAVE;
    uint8_t* sXw   = sXbuf + wave * 512;
    uint8_t* sXfbw = sXfb + wave * 128;
    const int rowBase = blockIdx.x * (NW * RPW) + wave * RPW;

    const uint8_t* fragp = sFrag + lane * 16;
    const uint8_t* b2p   = sB2 + lane * 8;

    f32x16_t cstA = ZERO16, cstB = ZERO16;
    float s0[16], s1[16];
    float wfa0 = 0.f, wfa1 = 0.f, wfb0 = 0.f, wfb1 = 0.f;

    // ================= encoder (4-step input chunks) =================
    // lane pair covers one row: lane&1 selects steps {0,1} vs {2,3} of chunk
    const float* gsrc = in_seq + (size_t)(rowBase + (lane >> 1)) * (T_IN * 2)
                               + (lane & 1) * 4;
    float4 pf = *(const float4*)gsrc;

    #pragma unroll 1
    for (int t = 0; t < T_IN; ++t) {
        if ((t & 3) == 0) {
            int row = lane >> 1, sb = (lane & 1) * 2;
            *(uint32_t*)(sXw + (sb + 0) * 128 + row * 4) = pk((__bf16)pf.x, (__bf16)pf.y);
            *(uint32_t*)(sXw + (sb + 1) * 128 + row * 4) = pk((__bf16)pf.z, (__bf16)pf.w);
            if (t < T_IN - 4)
                pf = *(const float4*)(gsrc + (t + 4) * 2);
        }
        uint32_t xpack = *(const uint32_t*)(sXw + (t & 3) * 128 + m * 4);
        do_step<false>(hb, fragp, b2p, m, kh, xpack,
                       cstA, cstB, wfa0, wfa1, wfb0, wfb1, s0, s1);
    }

    // ============ switch to decoder weights ============
    __syncthreads();
    stage_frags(WhhD, WihD, bihD, bhhD);
    __syncthreads();

    wfa0 = Wfc[m];        wfa1 = Wfc[64 + m];    // units 0..31
    wfb0 = Wfc[32 + m];   wfb1 = Wfc[96 + m];    // units 32..63
    const float nb0 = -LOG2E * bfc[0], nb1 = -LOG2E * bfc[1];

    uint32_t xpack = *(const uint32_t*)(sXw + 3 * 128 + m * 4);  // input_seq[:, -1]

    // ================= decoder =================
    #pragma unroll 1
    for (int td = 0; td < T_OUT; ++td) {
        #pragma unroll
        for (int j = 0; j < 16; ++j) { s0[j] = 0.f; s1[j] = 0.f; }
        do_step<true>(hb, fragp, b2p, m, kh, xpack,
                      cstA, cstB, wfa0, wfa1, wfb0, wfb1, s0, s1);
        // reduce across the 32 lanes of each half (rows live per half-wave)
        #pragma unroll
        for (int msk = 1; msk <= 16; msk <<= 1) {
            #pragma unroll
            for (int j = 0; j < 16; ++j) {
                s0[j] += __shfl_xor(s0[j], msk, 64);
                s1[j] += __shfl_xor(s1[j], msk, 64);
            }
        }
        // writer lanes (m==0 in each half) compute sigmoid, write out + feedback
        if (m == 0) {
            #pragma unroll
            for (int j = 0; j < 16; ++j) {
                int row = (j & 3) + 8 * (j >> 2) + 4 * kh;
                float p0 = rcp_f(1.f + ex2(__builtin_fmaf(-LOG2E, s0[j], nb0)));
                float p1 = rcp_f(1.f + ex2(__builtin_fmaf(-LOG2E, s1[j], nb1)));
                *(float2*)(out + ((size_t)(rowBase + row) * T_OUT + td) * 2)
                    = make_float2(p0, p1);
                *(uint32_t*)(sXfbw + row * 4) = pk((__bf16)p0, (__bf16)p1);
            }
        }
        xpack = *(const uint32_t*)(sXfbw + m * 4);   // same-wave LDS handoff
    }
}

extern "C" void kernel_launch(void* const* d_in, const int* in_sizes, int n_in,
                              void* d_out, int out_size, void* d_ws, size_t ws_size,
                              hipStream_t stream) {
    const float* in_seq = (const float*)d_in[0];
    const float* WihE = (const float*)d_in[1];
    const float* WhhE = (const float*)d_in[2];
    const float* bihE = (const float*)d_in[3];
    const float* bhhE = (const float*)d_in[4];
    const float* WihD = (const float*)d_in[5];
    const float* WhhD = (const float*)d_in[6];
    const float* bihD = (const float*)d_in[7];
    const float* bhhD = (const float*)d_in[8];
    const float* Wfc  = (const float*)d_in[9];
    const float* bfcp = (const float*)d_in[10];
    float* out = (float*)d_out;

    const int B = in_sizes[0] / (T_IN * 2);      // 131072
    dim3 grid(B / (NW * RPW)), block(NW * 64);   // 256 rows/block (8 waves x 32)
    hipLaunchKernelGGL(seq2seq_lstm, grid, block, 0, stream,
                       in_seq, WihE, WhhE, bihE, bhhE,
                       WihD, WhhD, bihD, bhhD, Wfc, bfcp, out);
}

// Round 2
// 2888.087 us; speedup vs baseline: 1.9975x; 1.9975x over previous
//
#include <hip/hip_runtime.h>
#include <stdint.h>

#define T_IN  128
#define T_OUT 50
#define NW    8                         // waves per block (512 threads)
#define RPW   32                        // batch rows per wave
#define HROW_BYTES 144                  // 128B h-row + 16B pad (9 x 16B, balanced banks)
#define HBUF_WAVE  (RPW * HROW_BYTES)   // 4608 B

typedef __bf16 bf16x8_t __attribute__((ext_vector_type(8)));
typedef float  f32x16_t __attribute__((ext_vector_type(16)));

#define LOG2E  1.4426950408889634f
#define LOG2E2 2.8853900817779268f

__device__ __forceinline__ float rcp_f(float x) { return __builtin_amdgcn_rcpf(x); }
__device__ __forceinline__ float ex2(float x)   { return __builtin_amdgcn_exp2f(x); }
__device__ __forceinline__ uint32_t pk(__bf16 a, __bf16 b) {
    return (uint32_t)__builtin_bit_cast(uint16_t, a) |
           ((uint32_t)__builtin_bit_cast(uint16_t, b) << 16);
}
#define MFMA32(A, B, C) __builtin_amdgcn_mfma_f32_32x32x16_bf16(A, B, C, 0, 0, 0)
#define ZERO16 (f32x16_t){0.f,0.f,0.f,0.f,0.f,0.f,0.f,0.f,0.f,0.f,0.f,0.f,0.f,0.f,0.f,0.f}

// 32x32x16 MFMA layouts:
//   C/D (HW-verified m74/m101): col = lane&31, row = (reg&3)+8*(reg>>2)+4*(lane>>5)
//   A: A[m = lane&31][k = (lane>>5)*8 + j];  B: B[k = (lane>>5)*8 + j][n = lane&31]
// Tiles: t = hf*4 + g  (g: 0=i,1=f,2=g,3=o; hf = unit col-half).
// exp2 folding: Whh/Wih/bias pre-scaled by log2e (i,f,o) / 2*log2e (g).
//
// OCCUPANCY PLAY: LDS shrunk to 78848B @ NW=8 -> 2 blk/CU = 16 waves/CU = 4/SIMD
// (r1 confirmed OccupancyPercent 22->44).
// LAUNCH-BOUNDS LESSON (r1 post-mortem): this toolchain treats the 2nd arg as
// CUDA-style min BLOCKS/CU. (512,4) -> 32 waves/CU -> VGPR cap 64 -> massive
// scratch spills (FETCH 1.8GB->16.5GB, 2x regression). (512,2) -> 16 waves/CU
// -> cap 128 = exactly this kernel's natural allocation (r0: 128, no spill).

template<bool DEC>
__device__ __forceinline__ void do_step(
    uint8_t* __restrict__ hb,           // wave's h buffer
    const uint8_t* __restrict__ fragp,  // sFrag + lane*16
    const uint8_t* __restrict__ b2p,    // sB2 + lane*8
    int m, int kh, uint32_t xpack,
    f32x16_t& cstA, f32x16_t& cstB,
    float wfa0, float wfa1, float wfb0, float wfb1,
    float (&s0)[16], float (&s1)[16])
{
    // A-frags: row m, k-groups 0..3 (units kk*16 + kh*8 + j)
    const uint8_t* ha = hb + m * HROW_BYTES + kh * 16;
    bf16x8_t a0 = *(const bf16x8_t*)(ha);
    bf16x8_t a1 = *(const bf16x8_t*)(ha + 32);
    bf16x8_t a2 = *(const bf16x8_t*)(ha + 64);
    bf16x8_t a3 = *(const bf16x8_t*)(ha + 96);
    union { bf16x8_t v; uint32_t u[4]; } ux;
    ux.u[0] = kh ? 0u : xpack;          // k=0,1 : x0, x1
    ux.u[1] = kh ? 0u : 0x00003F80u;    // k=2   : 1.0 (bias row)
    ux.u[2] = 0u; ux.u[3] = 0u;
    bf16x8_t ax = ux.v;

    #pragma unroll
    for (int hf = 0; hf < 2; ++hf) {
        f32x16_t acc[4];
        #pragma unroll
        for (int g = 0; g < 4; ++g) {
            const uint8_t* bp = fragp + (hf * 4 + g) * 4096;
            f32x16_t a = MFMA32(a0, *(const bf16x8_t*)(bp), ZERO16);
            a = MFMA32(a1, *(const bf16x8_t*)(bp + 1024), a);
            a = MFMA32(a2, *(const bf16x8_t*)(bp + 2048), a);
            a = MFMA32(a3, *(const bf16x8_t*)(bp + 3072), a);
            // x/bias slab: only k=0..3 nonzero; LDS holds zeros for kg=1 lanes
            uint2 d2 = *(const uint2*)(b2p + (hf * 4 + g) * 512);
            union { bf16x8_t v; uint32_t u[4]; } bu;
            bu.u[0] = d2.x; bu.u[1] = d2.y; bu.u[2] = 0u; bu.u[3] = 0u;
            acc[g] = MFMA32(ax, bu.v, a);
        }
        f32x16_t& cs = hf ? cstB : cstA;
        const float w0 = hf ? wfb0 : wfa0;
        const float w1 = hf ? wfb1 : wfa1;
        #pragma unroll
        for (int jp = 0; jp < 8; ++jp) {
            const int j0 = 2 * jp, j1 = 2 * jp + 1;
            float og[2], ec[2];
            #pragma unroll
            for (int jj = 0; jj < 2; ++jj) {
                const int j = j0 + jj;
                float ea  = ex2(-acc[0][j]);     // pre-scaled -> bare exp2
                float efv = ex2(-acc[1][j]);
                float egv = ex2(-acc[2][j]);     // g pre-scaled by 2*log2e
                float eov = ex2(-acc[3][j]);
                float pa = 1.f + ea, pfv = 1.f + efv, pg = 1.f + egv, po = 1.f + eov;
                float A  = pa * pg, Bq = pfv * po;
                float rr = rcp_f(A * Bq);
                float rA = rr * A;               // = 1/(pf*po)
                float rB = rr * Bq;              // = 1/(pa*pg)
                float igp = (1.f - egv) * rB;    // = i*g
                float fgt = rA * po;             // = sigmoid(f)
                float ogt = rA * pfv;            // = sigmoid(o)
                float cn  = fgt * cs[j] + igp;
                cs[j] = cn;
                float y = fminf(fmaxf(cn * LOG2E2, -43.f), 43.f);
                ec[jj] = ex2(-y);
                og[jj] = ogt;
            }
            float C0 = 1.f + ec[0], C1 = 1.f + ec[1];
            float rr2 = rcp_f(C0 * C1);
            float h0 = og[0] * (1.f - ec[0]) * rr2 * C1;
            float h1 = og[1] * (1.f - ec[1]) * rr2 * C0;
            if constexpr (DEC) {
                s0[j0] += h0 * w0; s1[j0] += h0 * w1;
                s0[j1] += h1 * w0; s1[j1] += h1 * w1;
            }
            const int r0 = (j0 & 3) + 8 * (j0 >> 2) + 4 * kh;
            const int r1 = (j1 & 3) + 8 * (j1 >> 2) + 4 * kh;
            *((__bf16*)(hb + r0 * HROW_BYTES + hf * 64) + m) = (__bf16)h0;
            *((__bf16*)(hb + r1 * HROW_BYTES + hf * 64) + m) = (__bf16)h1;
        }
    }
}

__global__ __launch_bounds__(512, 2) void seq2seq_lstm(
    const float* __restrict__ in_seq,
    const float* __restrict__ WihE, const float* __restrict__ WhhE,
    const float* __restrict__ bihE, const float* __restrict__ bhhE,
    const float* __restrict__ WihD, const float* __restrict__ WhhD,
    const float* __restrict__ bihD, const float* __restrict__ bhhD,
    const float* __restrict__ Wfc,  const float* __restrict__ bfc,
    float* __restrict__ out)
{
    __shared__ __align__(16) uint8_t sFrag[32768];          // 8 tiles x 4 kfrags x 1KB
    __shared__ __align__(16) uint8_t sB2[4096];             // 8 tiles x 64 lanes x 8B
    __shared__ __align__(16) uint8_t sHbuf[NW * HBUF_WAVE]; // 36864
    __shared__ __align__(16) uint8_t sXbuf[NW * 512];       // [step0..3][row0..31] u32-pack
    __shared__ __align__(16) uint8_t sXfb[NW * 128];        // decoder x feedback (u32-pack)
    // total 78848 B -> 2 blocks/CU (16 waves/CU = 4/SIMD) at VGPR cap 128

    const int tid  = threadIdx.x;
    const int lane = tid & 63;
    const int wave = tid >> 6;
    const int m    = lane & 31;
    const int kh   = lane >> 5;

    auto stage_frags = [&](const float* Whh, const float* Wih,
                           const float* bih, const float* bhh) {
        #pragma unroll 1
        for (int it = 0; it < 4; ++it) {
            int idx = it * 512 + tid;    // 0..2047 = frag(0..31) x lane(0..63)
            int ln  = idx & 63;
            int fg  = idx >> 6;          // fg = t*4 + kk
            int kk  = fg & 3;
            int t   = fg >> 2;
            int g   = t & 3;
            int hf  = t >> 2;
            int n   = ln & 31;
            int kg  = ln >> 5;
            float sc = (g == 2) ? LOG2E2 : LOG2E;
            const float* wr = Whh + (g * 64 + hf * 32 + n) * 64 + kk * 16 + kg * 8;
            uint32_t wv[4];
            #pragma unroll
            for (int jj = 0; jj < 4; ++jj)
                wv[jj] = pk((__bf16)(sc * wr[2 * jj]), (__bf16)(sc * wr[2 * jj + 1]));
            uint32_t* d = (uint32_t*)(sFrag + t * 4096 + kk * 1024 + ln * 16);
            d[0] = wv[0]; d[1] = wv[1]; d[2] = wv[2]; d[3] = wv[3];
        }
        // slab2: per (tile, lane): kg=0 lanes hold {Wih pair, bias pair}; kg=1 zeros
        {
            int ln = tid & 63;
            int t  = tid >> 6;           // 0..7
            int g  = t & 3;
            int hf = t >> 2;
            int n  = ln & 31;
            uint32_t u0 = 0u, u1 = 0u;
            if (ln < 32) {
                float sc = (g == 2) ? LOG2E2 : LOG2E;
                int col = g * 64 + hf * 32 + n;
                u0 = pk((__bf16)(sc * Wih[col * 2 + 0]), (__bf16)(sc * Wih[col * 2 + 1]));
                u1 = pk((__bf16)(sc * (bih[col] + bhh[col])), (__bf16)0.0f);
            }
            uint32_t* d = (uint32_t*)(sB2 + t * 512 + ln * 8);
            d[0] = u0; d[1] = u1;
        }
    };

    stage_frags(WhhE, WihE, bihE, bhhE);
    for (int i = tid; i < (NW * HBUF_WAVE) / 4; i += 512)
        ((uint32_t*)sHbuf)[i] = 0u;
    __syncthreads();
    // ---- no barriers inside the time loops: each wave owns its 32 rows ----

    uint8_t* hb    = sHbuf + wave * HBUF_WAVE;
    uint8_t* sXw   = sXbuf + wave * 512;
    uint8_t* sXfbw = sXfb + wave * 128;
    const int rowBase = blockIdx.x * (NW * RPW) + wave * RPW;

    const uint8_t* fragp = sFrag + lane * 16;
    const uint8_t* b2p   = sB2 + lane * 8;

    f32x16_t cstA = ZERO16, cstB = ZERO16;
    float s0[16], s1[16];
    float wfa0 = 0.f, wfa1 = 0.f, wfb0 = 0.f, wfb1 = 0.f;

    // ================= encoder (4-step input chunks) =================
    // lane pair covers one row: lane&1 selects steps {0,1} vs {2,3} of chunk
    const float* gsrc = in_seq + (size_t)(rowBase + (lane >> 1)) * (T_IN * 2)
                               + (lane & 1) * 4;
    float4 pf = *(const float4*)gsrc;

    #pragma unroll 1
    for (int t = 0; t < T_IN; ++t) {
        if ((t & 3) == 0) {
            int row = lane >> 1, sb = (lane & 1) * 2;
            *(uint32_t*)(sXw + (sb + 0) * 128 + row * 4) = pk((__bf16)pf.x, (__bf16)pf.y);
            *(uint32_t*)(sXw + (sb + 1) * 128 + row * 4) = pk((__bf16)pf.z, (__bf16)pf.w);
            if (t < T_IN - 4)
                pf = *(const float4*)(gsrc + (t + 4) * 2);
        }
        uint32_t xpack = *(const uint32_t*)(sXw + (t & 3) * 128 + m * 4);
        do_step<false>(hb, fragp, b2p, m, kh, xpack,
                       cstA, cstB, wfa0, wfa1, wfb0, wfb1, s0, s1);
    }

    // ============ switch to decoder weights ============
    __syncthreads();
    stage_frags(WhhD, WihD, bihD, bhhD);
    __syncthreads();

    wfa0 = Wfc[m];        wfa1 = Wfc[64 + m];    // units 0..31
    wfb0 = Wfc[32 + m];   wfb1 = Wfc[96 + m];    // units 32..63
    const float nb0 = -LOG2E * bfc[0], nb1 = -LOG2E * bfc[1];

    uint32_t xpack = *(const uint32_t*)(sXw + 3 * 128 + m * 4);  // input_seq[:, -1]

    // ================= decoder =================
    #pragma unroll 1
    for (int td = 0; td < T_OUT; ++td) {
        #pragma unroll
        for (int j = 0; j < 16; ++j) { s0[j] = 0.f; s1[j] = 0.f; }
        do_step<true>(hb, fragp, b2p, m, kh, xpack,
                      cstA, cstB, wfa0, wfa1, wfb0, wfb1, s0, s1);
        // reduce across the 32 lanes of each half (rows live per half-wave)
        #pragma unroll
        for (int msk = 1; msk <= 16; msk <<= 1) {
            #pragma unroll
            for (int j = 0; j < 16; ++j) {
                s0[j] += __shfl_xor(s0[j], msk, 64);
                s1[j] += __shfl_xor(s1[j], msk, 64);
            }
        }
        // writer lanes (m==0 in each half) compute sigmoid, write out + feedback
        if (m == 0) {
            #pragma unroll
            for (int j = 0; j < 16; ++j) {
                int row = (j & 3) + 8 * (j >> 2) + 4 * kh;
                float p0 = rcp_f(1.f + ex2(__builtin_fmaf(-LOG2E, s0[j], nb0)));
                float p1 = rcp_f(1.f + ex2(__builtin_fmaf(-LOG2E, s1[j], nb1)));
                *(float2*)(out + ((size_t)(rowBase + row) * T_OUT + td) * 2)
                    = make_float2(p0, p1);
                *(uint32_t*)(sXfbw + row * 4) = pk((__bf16)p0, (__bf16)p1);
            }
        }
        xpack = *(const uint32_t*)(sXfbw + m * 4);   // same-wave LDS handoff
    }
}

extern "C" void kernel_launch(void* const* d_in, const int* in_sizes, int n_in,
                              void* d_out, int out_size, void* d_ws, size_t ws_size,
                              hipStream_t stream) {
    const float* in_seq = (const float*)d_in[0];
    const float* WihE = (const float*)d_in[1];
    const float* WhhE = (const float*)d_in[2];
    const float* bihE = (const float*)d_in[3];
    const float* bhhE = (const float*)d_in[4];
    const float* WihD = (const float*)d_in[5];
    const float* WhhD = (const float*)d_in[6];
    const float* bihD = (const float*)d_in[7];
    const float* bhhD = (const float*)d_in[8];
    const float* Wfc  = (const float*)d_in[9];
    const float* bfcp = (const float*)d_in[10];
    float* out = (float*)d_out;

    const int B = in_sizes[0] / (T_IN * 2);      // 131072
    dim3 grid(B / (NW * RPW)), block(NW * 64);   // 256 rows/block (8 waves x 32)
    hipLaunchKernelGGL(seq2seq_lstm, grid, block, 0, stream,
                       in_seq, WihE, WhhE, bihE, bhhE,
                       WihD, WhhD, bihD, bhhD, Wfc, bfcp, out);
}

// Round 3
// 2145.997 us; speedup vs baseline: 2.6883x; 1.3458x over previous
//
#include <hip/hip_runtime.h>
#include <stdint.h>

#define T_IN  128
#define T_OUT 50
#define NW    8                         // waves per block (512 threads)
#define NPAIR 4                         // wave pairs; each pair owns 32 batch rows
#define RPW   32                        // batch rows per PAIR
#define HROW_BYTES 144                  // 128B h-row + 16B pad
#define HBUF_HALF  (RPW * HROW_BYTES)   // 4608 B per ping-pong buffer

typedef __bf16 bf16x8_t __attribute__((ext_vector_type(8)));
typedef float  f32x16_t __attribute__((ext_vector_type(16)));

#define LOG2E  1.4426950408889634f
#define LOG2E2 2.8853900817779268f

__device__ __forceinline__ float rcp_f(float x) { return __builtin_amdgcn_rcpf(x); }
__device__ __forceinline__ float ex2(float x)   { return __builtin_amdgcn_exp2f(x); }
__device__ __forceinline__ uint32_t pk(__bf16 a, __bf16 b) {
    return (uint32_t)__builtin_bit_cast(uint16_t, a) |
           ((uint32_t)__builtin_bit_cast(uint16_t, b) << 16);
}
#define MFMA32(A, B, C) __builtin_amdgcn_mfma_f32_32x32x16_bf16(A, B, C, 0, 0, 0)
#define ZERO16 (f32x16_t){0.f,0.f,0.f,0.f,0.f,0.f,0.f,0.f,0.f,0.f,0.f,0.f,0.f,0.f,0.f,0.f}

// REGISTER LESSON (r0/r1/r2 triangulation): launch_bounds 2nd arg = min WAVES
// per EU (LLVM semantics); CSV VGPR_Count = arch only, AGPRs (64 for acc[4])
// add on top for occupancy. Old structure = 192 total -> pinned at 2 waves/SIMD.
// THIS ROUND: hf-split wave pairs (cst 32->16, 20 MFMA/wave-step) + (i,g)/(f,o)
// gate pairing (acc 64->48 peak) + decoder FC via MFMA (kills s0/s1 + 160
// shfl/step). Target total <=128 under (512,4) -> 16 waves/CU.
// Pair sync: double-buffered h in LDS, ONE __syncthreads per step (ping-pong
// removes WAR; barrier orders RAW).

__device__ __forceinline__ void cell_step(
    bf16x8_t a0, bf16x8_t a1, bf16x8_t a2, bf16x8_t a3,
    uint32_t xpack, uint32_t kmask, int m, int rbase,
    const uint8_t* __restrict__ fragp,  // sFrag + hf*16384 + lane*16
    const uint8_t* __restrict__ b2p,    // sB2 + hf*1024 + m*8
    uint8_t* __restrict__ hw,           // hb_next + hf*64
    float (&cs)[16])
{
    union U { bf16x8_t v; uint32_t u[4]; };
    U ux;
    ux.u[0] = xpack & kmask;            // k=0,1 : x0,x1 (kh=0 lanes only)
    ux.u[1] = 0x00003F80u & kmask;      // k=2   : 1.0 bias row
    ux.u[2] = 0u; ux.u[3] = 0u;
    bf16x8_t ax = ux.v;

#define CHAIN(g, dst)                                                \
    { const uint8_t* bp = fragp + (g) * 4096;                        \
      f32x16_t t0 = MFMA32(a0, *(const bf16x8_t*)(bp), ZERO16);      \
      t0 = MFMA32(a1, *(const bf16x8_t*)(bp + 1024), t0);            \
      t0 = MFMA32(a2, *(const bf16x8_t*)(bp + 2048), t0);            \
      t0 = MFMA32(a3, *(const bf16x8_t*)(bp + 3072), t0);            \
      uint2 d2 = *(const uint2*)(b2p + (g) * 256);                   \
      U bu; bu.u[0] = d2.x & kmask; bu.u[1] = d2.y & kmask;          \
      bu.u[2] = 0u; bu.u[3] = 0u;                                    \
      dst = MFMA32(ax, bu.v, t0); }

    // pass 1: gates i (0) and g (2) -> igp = i*g   (acc peak stays at 32+16)
    f32x16_t ai, agv;
    CHAIN(0, ai)
    CHAIN(2, agv)
    float igp[16];
    #pragma unroll
    for (int j = 0; j < 16; ++j) {
        float ea = ex2(-ai[j]);          // pre-scaled -> bare exp2
        float eg = ex2(-agv[j]);         // g pre-scaled by 2*log2e
        igp[j] = (1.f - eg) * rcp_f((1.f + ea) * (1.f + eg));
    }
    // pass 2: gates f (1) and o (3) -> c,h
    f32x16_t af, ao;
    CHAIN(1, af)
    CHAIN(3, ao)
    #pragma unroll
    for (int jp = 0; jp < 8; ++jp) {
        const int j0 = 2 * jp, j1 = j0 + 1;
        float og[2], ec[2];
        #pragma unroll
        for (int jj = 0; jj < 2; ++jj) {
            const int j = j0 + jj;
            float ef = ex2(-af[j]);
            float eo = ex2(-ao[j]);
            float pf = 1.f + ef, po = 1.f + eo;
            float rr = rcp_f(pf * po);
            float fgt = rr * po;         // sigmoid(f)
            og[jj]    = rr * pf;         // sigmoid(o)
            float cn  = fgt * cs[j] + igp[j];
            cs[j] = cn;
            float y = fminf(fmaxf(cn * LOG2E2, -43.f), 43.f);
            ec[jj] = ex2(-y);
        }
        float C0 = 1.f + ec[0], C1 = 1.f + ec[1];
        float r2 = rcp_f(C0 * C1);
        float h0 = og[0] * (1.f - ec[0]) * r2 * C1;
        float h1 = og[1] * (1.f - ec[1]) * r2 * C0;
        const int r0 = (j0 & 3) + 8 * (j0 >> 2) + rbase;
        const int r1 = (j1 & 3) + 8 * (j1 >> 2) + rbase;
        *((__bf16*)(hw + r0 * HROW_BYTES) + m) = (__bf16)h0;
        *((__bf16*)(hw + r1 * HROW_BYTES) + m) = (__bf16)h1;
    }
#undef CHAIN
}

#define LOADA(base)                                   \
    { const uint8_t* ha_ = (base);                    \
      a0 = *(const bf16x8_t*)(ha_);                   \
      a1 = *(const bf16x8_t*)(ha_ + 32);              \
      a2 = *(const bf16x8_t*)(ha_ + 64);              \
      a3 = *(const bf16x8_t*)(ha_ + 96); }

__global__ __launch_bounds__(512, 4) void seq2seq_lstm(
    const float* __restrict__ in_seq,
    const float* __restrict__ WihE, const float* __restrict__ WhhE,
    const float* __restrict__ bihE, const float* __restrict__ bhhE,
    const float* __restrict__ WihD, const float* __restrict__ WhhD,
    const float* __restrict__ bihD, const float* __restrict__ bhhD,
    const float* __restrict__ Wfc,  const float* __restrict__ bfc,
    float* __restrict__ out)
{
    __shared__ __align__(16) uint8_t sFrag[32768];              // 8 tiles x 4 kfrags x 1KB
    __shared__ __align__(16) uint8_t sB2[2048];                 // 8 tiles x 32 x 8B (x/bias)
    __shared__ __align__(16) uint8_t sWfc[256];                 // FC B-slab (n<2 frags only)
    __shared__ __align__(16) uint8_t sHbuf[NPAIR * 2 * HBUF_HALF]; // 36864 (ping-pong)
    __shared__ __align__(16) uint8_t sXw[NPAIR * 1024];         // 8 slots x 32 rows x u32
    __shared__ __align__(16) uint8_t sXfb[NW * 128];            // per-wave feedback
    // total 77056 B -> 2 blocks/CU; with total regs <=128 -> 16 waves/CU

    const int tid  = threadIdx.x;
    const int lane = tid & 63;
    const int wave = tid >> 6;
    const int m    = lane & 31;
    const int kh   = lane >> 5;
    const int pair = wave >> 1;
    const int hf   = wave & 1;
    const uint32_t kmask = kh ? 0u : 0xFFFFFFFFu;
    const int rbase = kh * 4;

    auto stage_frags = [&](const float* Whh, const float* Wih,
                           const float* bih, const float* bhh) {
        #pragma unroll 1
        for (int it = 0; it < 4; ++it) {
            int idx = it * 512 + tid;    // 0..2047 = frag(0..31) x lane(0..63)
            int ln  = idx & 63;
            int fg  = idx >> 6;          // fg = t*4 + kk
            int kk  = fg & 3;
            int t   = fg >> 2;
            int g   = t & 3;
            int hfb = t >> 2;
            int n   = ln & 31;
            int kg  = ln >> 5;
            float sc = (g == 2) ? LOG2E2 : LOG2E;
            const float* wr = Whh + (g * 64 + hfb * 32 + n) * 64 + kk * 16 + kg * 8;
            uint32_t wv[4];
            #pragma unroll
            for (int jj = 0; jj < 4; ++jj)
                wv[jj] = pk((__bf16)(sc * wr[2 * jj]), (__bf16)(sc * wr[2 * jj + 1]));
            uint32_t* d = (uint32_t*)(sFrag + t * 4096 + kk * 1024 + ln * 16);
            d[0] = wv[0]; d[1] = wv[1]; d[2] = wv[2]; d[3] = wv[3];
        }
        // x/bias slab: only kg=0 data stored (32 lanes/tile); kg=1 zeroed via kmask
        if (tid < 256) {
            int t = tid >> 5, n = tid & 31;
            int g = t & 3, hfb = t >> 2;
            float sc = (g == 2) ? LOG2E2 : LOG2E;
            int col = g * 64 + hfb * 32 + n;
            uint2 q;
            q.x = pk((__bf16)(sc * Wih[col * 2 + 0]), (__bf16)(sc * Wih[col * 2 + 1]));
            q.y = pk((__bf16)(sc * (bih[col] + bhh[col])), (__bf16)0.0f);
            *(uint2*)(sB2 + t * 256 + n * 8) = q;
        }
    };

    stage_frags(WhhE, WihE, bihE, bhhE);
    for (int i = tid; i < (NPAIR * 2 * HBUF_HALF) / 4; i += 512)
        ((uint32_t*)sHbuf)[i] = 0u;

    uint8_t* sXwp = sXw + pair * 1024;
    const int rowBase = blockIdx.x * (NPAIR * RPW) + pair * RPW;

    // ---- encoder x staging: hf0 wave stages 4 steps/chunk, 8-slot ring ----
    const float* gsrc = in_seq + (size_t)(rowBase + (lane >> 1)) * (T_IN * 2)
                               + (lane & 1) * 4;
    float4 pf;
    if (hf == 0) {
        pf = *(const float4*)gsrc;                    // chunk 0 (steps 0..3)
        int row = lane >> 1, sb = (lane & 1) * 2;
        *(uint32_t*)(sXwp + (sb + 0) * 128 + row * 4) = pk((__bf16)pf.x, (__bf16)pf.y);
        *(uint32_t*)(sXwp + (sb + 1) * 128 + row * 4) = pk((__bf16)pf.z, (__bf16)pf.w);
        pf = *(const float4*)(gsrc + 8);              // prefetch chunk 1
    }
    __syncthreads();

    uint8_t* hbp = sHbuf + pair * (2 * HBUF_HALF);
    int cur = 0;
    const uint8_t* fragp = sFrag + hf * 16384 + lane * 16;
    const uint8_t* b2p   = sB2 + hf * 1024 + m * 8;
    const int haoff = m * HROW_BYTES + kh * 16;

    bf16x8_t a0, a1, a2, a3;
    LOADA(hbp + haoff);                               // zeros (h0)
    float cs[16];
    #pragma unroll
    for (int j = 0; j < 16; ++j) cs[j] = 0.f;

    // ================= encoder =================
    #pragma unroll 1
    for (int t = 0; t < T_IN; ++t) {
        uint32_t xpack = *(const uint32_t*)(sXwp + (t & 7) * 128 + m * 4);
        if (hf == 0 && (t & 3) == 3 && t < T_IN - 1) {
            int c = (t + 1) >> 2;                     // next chunk (1..31)
            int row = lane >> 1, sb = (lane & 1) * 2;
            int s0_ = (c * 4 + sb) & 7;
            *(uint32_t*)(sXwp + s0_ * 128 + row * 4)       = pk((__bf16)pf.x, (__bf16)pf.y);
            *(uint32_t*)(sXwp + (s0_ + 1) * 128 + row * 4) = pk((__bf16)pf.z, (__bf16)pf.w);
            if (c < 31) pf = *(const float4*)(gsrc + (c + 1) * 8);
        }
        uint8_t* hw = hbp + (cur ^ 1) * HBUF_HALF + hf * 64;
        cell_step(a0, a1, a2, a3, xpack, kmask, m, rbase, fragp, b2p, hw, cs);
        __syncthreads();                              // h halves visible
        cur ^= 1;
        LOADA(hbp + cur * HBUF_HALF + haoff);
    }

    // ============ switch to decoder weights ============
    // all waves are past the last encoder barrier; sFrag reads of t=127 done
    stage_frags(WhhD, WihD, bihD, bhhD);
    if (tid < 16) {                                   // FC B-slab: [kk][kg][n]
        int kk = tid >> 2, kg = (tid >> 1) & 1, n = tid & 1;
        const float* wr = Wfc + n * 64 + kk * 16 + kg * 8;
        uint32_t w[4];
        #pragma unroll
        for (int jj = 0; jj < 4; ++jj)
            w[jj] = pk((__bf16)wr[2 * jj], (__bf16)wr[2 * jj + 1]);
        uint32_t* d = (uint32_t*)(sWfc + kk * 64 + kg * 32 + n * 16);
        d[0] = w[0]; d[1] = w[1]; d[2] = w[2]; d[3] = w[3];
    }
    uint32_t xpack = *(const uint32_t*)(sXwp + 7 * 128 + m * 4);  // input_seq[:,-1]
    const float nb = -LOG2E * bfc[(m == 1) ? 1 : 0];
    uint8_t* sXfbw = sXfb + wave * 128;
    __syncthreads();

    // ================= decoder =================
    #pragma unroll 1
    for (int td = 0; td < T_OUT; ++td) {
        uint8_t* hw = hbp + (cur ^ 1) * HBUF_HALF + hf * 64;
        cell_step(a0, a1, a2, a3, xpack, kmask, m, rbase, fragp, b2p, hw, cs);
        __syncthreads();
        cur ^= 1;
        LOADA(hbp + cur * HBUF_HALF + haoff);         // h_new (also next step's A)
        // FC via MFMA: D[row][n] = sum_u h[row][u] * Wfc[n][u]; cols 0,1 valid.
        // lanes n>=2 read the n=(m&1) slot -> garbage cols, never consumed.
        const uint8_t* wfp = sWfc + kh * 32 + (m & 1) * 16;
        f32x16_t pacc = MFMA32(a0, *(const bf16x8_t*)(wfp),       ZERO16);
        pacc = MFMA32(a1, *(const bf16x8_t*)(wfp + 64),  pacc);
        pacc = MFMA32(a2, *(const bf16x8_t*)(wfp + 128), pacc);
        pacc = MFMA32(a3, *(const bf16x8_t*)(wfp + 192), pacc);
        if (m < 2) {                                  // lanes 0,1,32,33
            #pragma unroll
            for (int j = 0; j < 16; ++j) {
                int row = (j & 3) + 8 * (j >> 2) + rbase;
                float p = rcp_f(1.f + ex2(__builtin_fmaf(-LOG2E, pacc[j], nb)));
                if (hf == 0)
                    out[((size_t)(rowBase + row) * T_OUT + td) * 2 + m] = p;
                *(uint16_t*)(sXfbw + row * 4 + m * 2) =
                    __builtin_bit_cast(uint16_t, (__bf16)p);
            }
        }
        xpack = *(const uint32_t*)(sXfbw + m * 4);    // same-wave LDS handoff
    }
}

extern "C" void kernel_launch(void* const* d_in, const int* in_sizes, int n_in,
                              void* d_out, int out_size, void* d_ws, size_t ws_size,
                              hipStream_t stream) {
    const float* in_seq = (const float*)d_in[0];
    const float* WihE = (const float*)d_in[1];
    const float* WhhE = (const float*)d_in[2];
    const float* bihE = (const float*)d_in[3];
    const float* bhhE = (const float*)d_in[4];
    const float* WihD = (const float*)d_in[5];
    const float* WhhD = (const float*)d_in[6];
    const float* bihD = (const float*)d_in[7];
    const float* bhhD = (const float*)d_in[8];
    const float* Wfc  = (const float*)d_in[9];
    const float* bfcp = (const float*)d_in[10];
    float* out = (float*)d_out;

    const int B = in_sizes[0] / (T_IN * 2);          // 131072
    dim3 grid(B / (NPAIR * RPW)), block(NW * 64);    // 128 rows/block, 512 thr
    hipLaunchKernelGGL(seq2seq_lstm, grid, block, 0, stream,
                       in_seq, WihE, WhhE, bihE, bhhE,
                       WihD, WhhD, bihD, bhhD, Wfc, bfcp, out);
}